// Round 6
// baseline (290.946 us; speedup 1.0000x reference)
//
#include <hip/hip_runtime.h>
#include <hip/hip_bf16.h>
#include <math.h>

// ---------------------------------------------------------------------------
// ViT Attention block: x[8,1024,768] -> qkv -> MHA(12 heads, d=64) -> proj
// GEMM v4: 128x128 tile, BK=64, double-buffered LDS with COUNTED vmcnt +
// raw s_barrier (T4): prefetch loads stay in flight across barriers
// (vmcnt(8) waits only previous buffer's loads; never vmcnt(0) in loop).
// T2 XOR swizzle (conflicts measured 0 in r3/r4), T1 bijective XCD swizzle.
// Flash v3: NO LDS staging (m169: K/V L2-resident at S=1024 -> staging is
// pure overhead). K/V fragments read directly from global; zero barriers.
// (Resubmission of round-5 source — bench never ran, GPU timeout.)
// ---------------------------------------------------------------------------

typedef __bf16 bf16;
typedef __bf16 bf16x8 __attribute__((ext_vector_type(8)));
typedef __bf16 bf16x4 __attribute__((ext_vector_type(4)));
typedef float  f32x4  __attribute__((ext_vector_type(4)));
typedef short  s16x4  __attribute__((ext_vector_type(4)));

#define AS1 __attribute__((address_space(1)))
#define AS3 __attribute__((address_space(3)))

static __device__ __forceinline__ f32x4 mfma16x16x16bf16(s16x4 a, s16x4 b, f32x4 c) {
#if __has_builtin(__builtin_amdgcn_mfma_f32_16x16x16bf16_1k)
    return __builtin_amdgcn_mfma_f32_16x16x16bf16_1k(a, b, c, 0, 0, 0);
#else
    asm("v_mfma_f32_16x16x16_bf16 %0, %1, %2, %0" : "+v"(c) : "v"(a), "v"(b));
    return c;
#endif
}

// ---------------- fused fp32 -> bf16 convert (3 arrays, 1 launch) ----------
__global__ void cvt3_f32_bf16(const float* __restrict__ s1, bf16* __restrict__ d1, int n1,
                              const float* __restrict__ s2, bf16* __restrict__ d2, int n2,
                              const float* __restrict__ s3, bf16* __restrict__ d3, int n3) {
    int i = blockIdx.x * blockDim.x + threadIdx.x;
    int stride = gridDim.x * blockDim.x;
    int total = n1 + n2 + n3;
    for (; i < total; i += stride) {
        const float* s; bf16* d; int k;
        if (i < n1)            { s = s1; d = d1; k = i; }
        else if (i < n1 + n2)  { s = s2; d = d2; k = i - n1; }
        else                   { s = s3; d = d3; k = i - n1 - n2; }
        f32x4 a = ((const f32x4*)s)[2 * (size_t)k];
        f32x4 bv = ((const f32x4*)s)[2 * (size_t)k + 1];
        bf16x8 o;
        o[0] = (bf16)a[0]; o[1] = (bf16)a[1]; o[2] = (bf16)a[2]; o[3] = (bf16)a[3];
        o[4] = (bf16)bv[0]; o[5] = (bf16)bv[1]; o[6] = (bf16)bv[2]; o[7] = (bf16)bv[3];
        ((bf16x8*)d)[k] = o;
    }
}

// ---------------- GEMM v4: C[M,N] = A[M,K] * Bw[N,K]^T ---------------------
// Schedule per K-step (counted-vmcnt, m201 mechanism):
//   STAGE(buf^1, ks+1)            // 8 new loads -> 16 in flight
//   s_waitcnt vmcnt(8)            // old buffer's 8 retired; new 8 IN FLIGHT
//   s_barrier                     // all waves' buf-c data visible
//   ds_read frags + 32 MFMA       // new loads retire under this compute
//   s_waitcnt lgkmcnt(0)          // my reads of buf c complete
//   s_barrier                     // safe to overwrite buf c next iter
template <int EPI, int GY>
__launch_bounds__(256, 2)
__global__ void gemm_bt(const bf16* __restrict__ A, const bf16* __restrict__ Bw, int Kdim,
                        bf16* __restrict__ qo, bf16* __restrict__ ko, bf16* __restrict__ vto,
                        float* __restrict__ outf, const float* __restrict__ bias) {
    __shared__ alignas(16) bf16 As[2][128 * 64];
    __shared__ alignas(16) bf16 Bs[2][128 * 64];
    const int tid  = threadIdx.x;
    const int lane = tid & 63;
    const int wave = tid >> 6;
    const int lo = lane & 15, hi = lane >> 4;
    const int wr = wave >> 1, wc = wave & 1;

    // T1: bijective XCD remap (nwg = 64*GY, divisible by 8)
    const int bid = blockIdx.x;
    const int xcd = bid & 7, idx = bid >> 3;
    const int m0 = (xcd * 8 + (idx & 7)) * 128;   // 8 m-panels per XCD
    const int n0 = (idx >> 3) * 128;

    const int s_phys = tid & 7;
    f32x4 acc[4][4] = {};

#define STAGE(buf, ks)                                                          \
    {                                                                           \
        _Pragma("unroll")                                                       \
        for (int i = 0; i < 4; ++i) {                                           \
            int row = ((i * 256 + tid) >> 3);                                   \
            int sl  = s_phys ^ (row & 7);                                       \
            __builtin_amdgcn_global_load_lds(                                   \
                (const AS1 void*)(A + (size_t)(m0 + row) * Kdim + (ks) * 64 + sl * 8), \
                (AS3 void*)(&As[buf][0] + (i * 256 + wave * 64) * 8), 16, 0, 0);\
            __builtin_amdgcn_global_load_lds(                                   \
                (const AS1 void*)(Bw + (size_t)(n0 + row) * Kdim + (ks) * 64 + sl * 8), \
                (AS3 void*)(&Bs[buf][0] + (i * 256 + wave * 64) * 8), 16, 0, 0);\
        }                                                                       \
    }

    const int KS = Kdim >> 6;  // 768 -> 12 K-steps
    STAGE(0, 0);               // prologue: 8 loads in flight

    for (int ks = 0; ks < KS; ++ks) {
        const int c = ks & 1;
        if (ks + 1 < KS) {
            STAGE(c ^ 1, ks + 1);                            // +8 -> 16 in flight
            asm volatile("s_waitcnt vmcnt(8)" ::: "memory"); // old 8 done
        } else {
            asm volatile("s_waitcnt vmcnt(0)" ::: "memory");
        }
        __builtin_amdgcn_s_barrier();

        bf16x8 af[4][2], bfr[4][2];
#pragma unroll
        for (int kk = 0; kk < 2; ++kk) {
            const int sl = ((kk << 2) | hi) ^ (lo & 7);
#pragma unroll
            for (int i = 0; i < 4; ++i)
                af[i][kk] = *(const bf16x8*)&As[c][(wr * 64 + i * 16 + lo) * 64 + sl * 8];
#pragma unroll
            for (int j = 0; j < 4; ++j)
                bfr[j][kk] = *(const bf16x8*)&Bs[c][(wc * 64 + j * 16 + lo) * 64 + sl * 8];
        }
#pragma unroll
        for (int i = 0; i < 4; ++i)
#pragma unroll
            for (int j = 0; j < 4; ++j) {
                acc[i][j] = __builtin_amdgcn_mfma_f32_16x16x32_bf16(af[i][0], bfr[j][0], acc[i][j], 0, 0, 0);
                acc[i][j] = __builtin_amdgcn_mfma_f32_16x16x32_bf16(af[i][1], bfr[j][1], acc[i][j], 0, 0, 0);
            }

        asm volatile("s_waitcnt lgkmcnt(0)" ::: "memory");   // my buf-c reads done
        __builtin_amdgcn_s_barrier();                        // all waves done reading
    }
#undef STAGE

    // epilogue. C frag layout: row=(lane>>4)*4+r, col=lane&15  [m89-verified]
    if (EPI == 0) {
        const int part = n0 / 768;
#pragma unroll
        for (int i = 0; i < 4; ++i) {
            int grow = m0 + wr * 64 + i * 16 + (hi << 2);
            int b = grow >> 10;
            int n = grow & 1023;
#pragma unroll
            for (int j = 0; j < 4; ++j) {
                int col = n0 + wc * 64 + j * 16 + lo;
                int rem = col - part * 768;
                int h = rem >> 6, d = rem & 63;
#pragma unroll
                for (int r = 0; r < 4; ++r) {
                    bf16 v = (bf16)acc[i][j][r];
                    int nn = n + r;
                    if (part == 0)
                        qo[((size_t)(b * 12 + h) * 1024 + nn) * 64 + d] = v;
                    else if (part == 1)
                        ko[((size_t)(b * 12 + h) * 1024 + nn) * 64 + d] = v;
                    else
                        vto[((size_t)(b * 12 + h) * 64 + d) * 1024 + nn] = v;
                }
            }
        }
    } else {
#pragma unroll
        for (int i = 0; i < 4; ++i) {
            int grow = m0 + wr * 64 + i * 16 + (hi << 2);
#pragma unroll
            for (int j = 0; j < 4; ++j) {
                int col = n0 + wc * 64 + j * 16 + lo;
                float bv = bias[col];
#pragma unroll
                for (int r = 0; r < 4; ++r)
                    outf[(size_t)(grow + r) * 768 + col] = acc[i][j][r] + bv;
            }
        }
    }
}

// ---------------- flash attention v3: no LDS, no barriers ------------------
// m169 evidence: at S=1024 the per-head K/V (128KB) is L2-resident ->
// LDS staging is pure overhead. Fragments read directly from global.
// XCD-sticky: 12 heads per XCD = 3MB K+V < 4MB L2. Waves fully independent.
__launch_bounds__(256, 3)
__global__ void flash_attn(const bf16* __restrict__ qg, const bf16* __restrict__ kg,
                           const bf16* __restrict__ vtg, bf16* __restrict__ og) {
    const int tid = threadIdx.x, lane = tid & 63, wave = tid >> 6;
    const int lo = lane & 15, hi = lane >> 4;

    const int bid = blockIdx.x;                 // 0..767
    const int xcd = bid & 7, idx = bid >> 3;
    const int head = xcd * 12 + (idx >> 3);
    const int q0 = (idx & 7) * 128;
    const int b = head / 12, h = head % 12;

    const size_t baseQK = (size_t)head * 1024 * 64;  // [B,H,N,D]
    const size_t baseVt = (size_t)head * 64 * 1024;  // [B,H,D,N]

    // Q frags (B-operand): col q = jq*16+lo, k = kk*32+hi*8+e. Pre-scale 1/8.
    bf16x8 qf[2][2];
#pragma unroll
    for (int jq = 0; jq < 2; ++jq)
#pragma unroll
        for (int kk = 0; kk < 2; ++kk) {
            bf16x8 v = *(const bf16x8*)&qg[baseQK +
                (size_t)(q0 + wave * 32 + jq * 16 + lo) * 64 + kk * 32 + hi * 8];
#pragma unroll
            for (int e = 0; e < 8; ++e) v[e] = (bf16)((float)v[e] * 0.125f);
            qf[jq][kk] = v;
        }

    f32x4 of[4][2] = {};          // O^T: d = jd*16+hi*4+r, q = jq*16+lo
    float lsum[2] = {0.f, 0.f};

    for (int t = 0; t < 16; ++t) {
        // K frags direct from global: K[t*64 + j*16+lo][kk*32 + hi*8]
        const bf16* kt = kg + baseQK + (size_t)t * 64 * 64;
        bf16x8 kf[4][2];
#pragma unroll
        for (int j = 0; j < 4; ++j)
#pragma unroll
            for (int kk = 0; kk < 2; ++kk)
                kf[j][kk] = *(const bf16x8*)&kt[(j * 16 + lo) * 64 + kk * 32 + hi * 8];

        // S^T = K * Q^T: D[kv][q], kv = j*16 + hi*4+r, q = jq*16+lo
        __builtin_amdgcn_s_setprio(1);
        f32x4 st[4][2];
#pragma unroll
        for (int j = 0; j < 4; ++j)
#pragma unroll
            for (int jq = 0; jq < 2; ++jq) {
                f32x4 z = {0.f, 0.f, 0.f, 0.f};
                z = __builtin_amdgcn_mfma_f32_16x16x32_bf16(kf[j][0], qf[jq][0], z, 0, 0, 0);
                st[j][jq] = __builtin_amdgcn_mfma_f32_16x16x32_bf16(kf[j][1], qf[jq][1], z, 0, 0, 0);
            }
        __builtin_amdgcn_s_setprio(0);

        // static-max softmax: p = exp(S-10); accumulate l; pack bf16x4
        s16x4 pb[4][2];
#pragma unroll
        for (int j = 0; j < 4; ++j)
#pragma unroll
            for (int jq = 0; jq < 2; ++jq) {
                f32x4 p;
#pragma unroll
                for (int r = 0; r < 4; ++r) p[r] = __expf(st[j][jq][r] - 10.0f);
                lsum[jq] += (p[0] + p[1]) + (p[2] + p[3]);
                bf16x4 pk;
#pragma unroll
                for (int r = 0; r < 4; ++r) pk[r] = (bf16)p[r];
                pb[j][jq] = __builtin_bit_cast(s16x4, pk);
            }

        // PV direct from global: va = Vt[jd*16+lo][t*64 + j*16 + hi*4]
        __builtin_amdgcn_s_setprio(1);
#pragma unroll
        for (int jd = 0; jd < 4; ++jd) {
#pragma unroll
            for (int j = 0; j < 4; ++j) {
                s16x4 va = *(const s16x4*)&vtg[baseVt +
                    (size_t)(jd * 16 + lo) * 1024 + t * 64 + j * 16 + hi * 4];
#pragma unroll
                for (int jq = 0; jq < 2; ++jq)
                    of[jd][jq] = mfma16x16x16bf16(va, pb[j][jq], of[jd][jq]);
            }
        }
        __builtin_amdgcn_s_setprio(0);
    }

    // l: hi-groups hold disjoint kv partitions -> one butterfly at the end
#pragma unroll
    for (int jq = 0; jq < 2; ++jq) {
        lsum[jq] += __shfl_xor(lsum[jq], 16);
        lsum[jq] += __shfl_xor(lsum[jq], 32);
    }

    // O = O^T/l: lane q = jq*16+lo, d = jd*16+hi*4+r (8B stores)
#pragma unroll
    for (int jq = 0; jq < 2; ++jq) {
        float rl = 1.0f / lsum[jq];
        int n = q0 + wave * 32 + jq * 16 + lo;
#pragma unroll
        for (int jd = 0; jd < 4; ++jd) {
            bf16x4 o;
#pragma unroll
            for (int r = 0; r < 4; ++r) o[r] = (bf16)(of[jd][jq][r] * rl);
            *(bf16x4*)&og[((size_t)b * 1024 + n) * 768 + h * 64 + jd * 16 + hi * 4] = o;
        }
    }
}

// ---------------------------------------------------------------------------
extern "C" void kernel_launch(void* const* d_in, const int* in_sizes, int n_in,
                              void* d_out, int out_size, void* d_ws, size_t ws_size,
                              hipStream_t stream) {
    const float* x      = (const float*)d_in[0];
    const float* w_qkv  = (const float*)d_in[1];
    const float* w_proj = (const float*)d_in[2];
    const float* b_proj = (const float*)d_in[3];
    float* out = (float*)d_out;

    bf16* xb     = (bf16*)d_ws;
    bf16* wqkvb  = xb + (size_t)8192 * 768;
    bf16* wprojb = wqkvb + (size_t)2304 * 768;
    bf16* qb     = wprojb + (size_t)768 * 768;
    bf16* kb     = qb + (size_t)96 * 1024 * 64;
    bf16* vtb    = kb + (size_t)96 * 1024 * 64;
    bf16* aob    = vtb + (size_t)96 * 1024 * 64;

    cvt3_f32_bf16<<<1024, 256, 0, stream>>>(x, xb, 8192 * 768 / 8,
                                            w_qkv, wqkvb, 2304 * 768 / 8,
                                            w_proj, wprojb, 768 * 768 / 8);

    gemm_bt<0, 18><<<64 * 18, 256, 0, stream>>>(xb, wqkvb, 768, qb, kb, vtb, nullptr, nullptr);
    flash_attn<<<768, 256, 0, stream>>>(qb, kb, vtb, aob);
    gemm_bt<1, 6><<<64 * 6, 256, 0, stream>>>(aob, wprojb, 768, nullptr, nullptr, nullptr, out, b_proj);
}

// Round 8
// 239.071 us; speedup vs baseline: 1.2170x; 1.2170x over previous
//
#include <hip/hip_runtime.h>
#include <hip/hip_bf16.h>
#include <math.h>

// ---------------------------------------------------------------------------
// ViT Attention block: x[8,1024,768] -> qkv -> MHA(12 heads, d=64) -> proj
// GEMM v5: 256x256 tile, BK=64, 512 thr / 8 waves (2Mx4N), 128KB dbuf LDS,
// m201-style counted-vmcnt schedule. Stage order per K-tile: B0..B3,A0,A2,A1,A3.
//   boundary: vmcnt(2)+barrier  (B+A0+A2 ready; A1,A3 still in flight)
//   mid:      vmcnt(8)+barrier  (in-order retire forces A1,A3; next tile's 8 in flight)
// vmcnt never 0 in the main loop (T4); T2 XOR swizzle (0 conflicts r3-r6);
// T5 setprio around MFMA clusters; bijective XCD chunking.
// Flash v4 = r2 structure + T14 fix: next-tile loads issued AFTER the
// visibility barrier so their drain (at the post-compute barrier) is hidden.
// (Resubmission of round-7 source — bench never ran, GPU timeout.)
// ---------------------------------------------------------------------------

typedef __bf16 bf16;
typedef __bf16 bf16x8 __attribute__((ext_vector_type(8)));
typedef __bf16 bf16x4 __attribute__((ext_vector_type(4)));
typedef float  f32x4  __attribute__((ext_vector_type(4)));
typedef short  s16x4  __attribute__((ext_vector_type(4)));

#define AS1 __attribute__((address_space(1)))
#define AS3 __attribute__((address_space(3)))

static __device__ __forceinline__ f32x4 mfma16x16x16bf16(s16x4 a, s16x4 b, f32x4 c) {
#if __has_builtin(__builtin_amdgcn_mfma_f32_16x16x16bf16_1k)
    return __builtin_amdgcn_mfma_f32_16x16x16bf16_1k(a, b, c, 0, 0, 0);
#else
    asm("v_mfma_f32_16x16x16_bf16 %0, %1, %2, %0" : "+v"(c) : "v"(a), "v"(b));
    return c;
#endif
}

// ---------------- fused fp32 -> bf16 convert (3 arrays, 1 launch) ----------
__global__ void cvt3_f32_bf16(const float* __restrict__ s1, bf16* __restrict__ d1, int n1,
                              const float* __restrict__ s2, bf16* __restrict__ d2, int n2,
                              const float* __restrict__ s3, bf16* __restrict__ d3, int n3) {
    int i = blockIdx.x * blockDim.x + threadIdx.x;
    int stride = gridDim.x * blockDim.x;
    int total = n1 + n2 + n3;
    for (; i < total; i += stride) {
        const float* s; bf16* d; int k;
        if (i < n1)            { s = s1; d = d1; k = i; }
        else if (i < n1 + n2)  { s = s2; d = d2; k = i - n1; }
        else                   { s = s3; d = d3; k = i - n1 - n2; }
        f32x4 a = ((const f32x4*)s)[2 * (size_t)k];
        f32x4 bv = ((const f32x4*)s)[2 * (size_t)k + 1];
        bf16x8 o;
        o[0] = (bf16)a[0]; o[1] = (bf16)a[1]; o[2] = (bf16)a[2]; o[3] = (bf16)a[3];
        o[4] = (bf16)bv[0]; o[5] = (bf16)bv[1]; o[6] = (bf16)bv[2]; o[7] = (bf16)bv[3];
        ((bf16x8*)d)[k] = o;
    }
}

// ---------------- GEMM v5: C[M,N] = A[M,K] * Bw[N,K]^T, 256x256 tile -------
// grid = 8 XCD chunks x (4 m-tiles x NT n-tiles). wave (wr=w>>2, wc=w&3)
// owns 128x64 = 8x4 16x16 frags. Stage instr = 64 rows (128B/row, 8 slots);
// swizzle: phys slot s at row r holds logical s^(r&7) (involution).
template <int EPI, int NT>
__launch_bounds__(512, 2)
__global__ void gemm_bt(const bf16* __restrict__ A, const bf16* __restrict__ Bw, int Kdim,
                        bf16* __restrict__ qo, bf16* __restrict__ ko, bf16* __restrict__ vto,
                        float* __restrict__ outf, const float* __restrict__ bias) {
    __shared__ alignas(16) bf16 As[2][256 * 64];
    __shared__ alignas(16) bf16 Bs[2][256 * 64];
    const int tid  = threadIdx.x;
    const int lane = tid & 63;
    const int wave = tid >> 6;
    const int lo = lane & 15, hi = lane >> 4;
    const int wr = wave >> 2, wc = wave & 3;

    // bijective XCD chunking: xcd owns 4 consecutive m-tiles x all NT n-tiles
    const int bid = blockIdx.x;
    const int xcd = bid / (4 * NT), idx = bid % (4 * NT);
    const int m0 = (xcd * 4 + idx / NT) * 256;
    const int n0 = (idx % NT) * 256;

    const int trow = tid >> 3;                    // 0..63 (row within 64-row chunk)
    const int sl   = (tid & 7) ^ (trow & 7);      // inverse-swizzled source slot

    f32x4 acc[8][4] = {};

#define GLOAD(srcp, dstp) \
    __builtin_amdgcn_global_load_lds((const AS1 void*)(srcp), (AS3 void*)(dstp), 16, 0, 0)
    // order: B0,B1,B2,B3 (all n-rows), A0 (rows 0-63), A2 (128-191), A1 (64-127), A3 (192-255)
#define STAGE8(buf, kt)                                                                   \
    {                                                                                     \
        _Pragma("unroll")                                                                 \
        for (int q = 0; q < 4; ++q)                                                       \
            GLOAD(Bw + (size_t)(n0 + q * 64 + trow) * Kdim + (kt) * 64 + sl * 8,          \
                  &Bs[buf][0] + q * 4096 + wave * 512);                                   \
        GLOAD(A + (size_t)(m0 +   0 + trow) * Kdim + (kt) * 64 + sl * 8,                  \
              &As[buf][0] + 0 * 4096 + wave * 512);                                       \
        GLOAD(A + (size_t)(m0 + 128 + trow) * Kdim + (kt) * 64 + sl * 8,                  \
              &As[buf][0] + 2 * 4096 + wave * 512);                                       \
        GLOAD(A + (size_t)(m0 +  64 + trow) * Kdim + (kt) * 64 + sl * 8,                  \
              &As[buf][0] + 1 * 4096 + wave * 512);                                       \
        GLOAD(A + (size_t)(m0 + 192 + trow) * Kdim + (kt) * 64 + sl * 8,                  \
              &As[buf][0] + 3 * 4096 + wave * 512);                                       \
    }

    const int KT = Kdim >> 6;  // 768 -> 12 K-tiles
    STAGE8(0, 0);
    asm volatile("s_waitcnt vmcnt(2)" ::: "memory");  // B,A0,A2 of kt0 ready
    __builtin_amdgcn_s_barrier();
    __builtin_amdgcn_sched_barrier(0);

    for (int kt = 0; kt < KT; ++kt) {
        const int c = kt & 1;
        if (kt + 1 < KT) STAGE8(c ^ 1, kt + 1);   // buf c^1 free (kt-1 reads done)

        // B-frags for this wave (rows wc*64 + j*16 + lo)
        bf16x8 bfrag[4][2];
#pragma unroll
        for (int kk = 0; kk < 2; ++kk) {
            const int slr = ((kk << 2) | hi) ^ (lo & 7);
#pragma unroll
            for (int j = 0; j < 4; ++j)
                bfrag[j][kk] = *(const bf16x8*)&Bs[c][(wc * 64 + j * 16 + lo) * 64 + slr * 8];
        }

        // half 0: A rows wr*128 + [0,64)  (covered by A0/A2, guaranteed at boundary)
        bf16x8 afr[4][2];
#pragma unroll
        for (int kk = 0; kk < 2; ++kk) {
            const int slr = ((kk << 2) | hi) ^ (lo & 7);
#pragma unroll
            for (int i = 0; i < 4; ++i)
                afr[i][kk] = *(const bf16x8*)&As[c][(wr * 128 + i * 16 + lo) * 64 + slr * 8];
        }
        __builtin_amdgcn_s_setprio(1);
#pragma unroll
        for (int i = 0; i < 4; ++i)
#pragma unroll
            for (int j = 0; j < 4; ++j) {
                acc[i][j] = __builtin_amdgcn_mfma_f32_16x16x32_bf16(afr[i][0], bfrag[j][0], acc[i][j], 0, 0, 0);
                acc[i][j] = __builtin_amdgcn_mfma_f32_16x16x32_bf16(afr[i][1], bfrag[j][1], acc[i][j], 0, 0, 0);
            }
        __builtin_amdgcn_s_setprio(0);

        // mid sync: force A1,A3 of kt (oldest outstanding); next tile's 8 stay in flight
        if (kt + 1 < KT) { asm volatile("s_waitcnt vmcnt(8)" ::: "memory"); }
        else             { asm volatile("s_waitcnt vmcnt(0)" ::: "memory"); }
        __builtin_amdgcn_s_barrier();
        __builtin_amdgcn_sched_barrier(0);

        // half 1: A rows wr*128 + [64,128)
#pragma unroll
        for (int kk = 0; kk < 2; ++kk) {
            const int slr = ((kk << 2) | hi) ^ (lo & 7);
#pragma unroll
            for (int i = 0; i < 4; ++i)
                afr[i][kk] = *(const bf16x8*)&As[c][(wr * 128 + 64 + i * 16 + lo) * 64 + slr * 8];
        }
        __builtin_amdgcn_s_setprio(1);
#pragma unroll
        for (int i = 0; i < 4; ++i)
#pragma unroll
            for (int j = 0; j < 4; ++j) {
                acc[4 + i][j] = __builtin_amdgcn_mfma_f32_16x16x32_bf16(afr[i][0], bfrag[j][0], acc[4 + i][j], 0, 0, 0);
                acc[4 + i][j] = __builtin_amdgcn_mfma_f32_16x16x32_bf16(afr[i][1], bfrag[j][1], acc[4 + i][j], 0, 0, 0);
            }
        __builtin_amdgcn_s_setprio(0);

        // boundary sync: B,A0,A2 of kt+1 ready; its A1,A3 remain in flight
        if (kt + 1 < KT) {
            asm volatile("s_waitcnt vmcnt(2)" ::: "memory");
            __builtin_amdgcn_s_barrier();
            __builtin_amdgcn_sched_barrier(0);
        }
    }
#undef STAGE8
#undef GLOAD

    // epilogue. C frag layout: row=(lane>>4)*4+r, col=lane&15  [m89-verified]
    if (EPI == 0) {
        const int part = n0 / 768;
#pragma unroll
        for (int i = 0; i < 8; ++i) {
            int grow = m0 + wr * 128 + i * 16 + (hi << 2);
            int b = grow >> 10;
            int n = grow & 1023;
#pragma unroll
            for (int j = 0; j < 4; ++j) {
                int col = n0 + wc * 64 + j * 16 + lo;
                int rem = col - part * 768;
                int h = rem >> 6, d = rem & 63;
#pragma unroll
                for (int r = 0; r < 4; ++r) {
                    bf16 v = (bf16)acc[i][j][r];
                    int nn = n + r;
                    if (part == 0)
                        qo[((size_t)(b * 12 + h) * 1024 + nn) * 64 + d] = v;
                    else if (part == 1)
                        ko[((size_t)(b * 12 + h) * 1024 + nn) * 64 + d] = v;
                    else
                        vto[((size_t)(b * 12 + h) * 64 + d) * 1024 + nn] = v;
                }
            }
        }
    } else {
#pragma unroll
        for (int i = 0; i < 8; ++i) {
            int grow = m0 + wr * 128 + i * 16 + (hi << 2);
#pragma unroll
            for (int j = 0; j < 4; ++j) {
                int col = n0 + wc * 64 + j * 16 + lo;
                float bv = bias[col];
#pragma unroll
                for (int r = 0; r < 4; ++r)
                    outf[(size_t)(grow + r) * 768 + col] = acc[i][j][r] + bv;
            }
        }
    }
}

// ---------------- flash attention v4: LDS-staged, T14 fixed ----------------
// r2 structure (best measured: ~55us). Per tile t:
//   barrier(a): tile t visible -> issue t+1 global loads (drain lands at (b),
//   AFTER compute -> hidden) -> QK^T/softmax/PV -> barrier(b) -> ds_write t+1.
__launch_bounds__(256, 3)
__global__ void flash_attn(const bf16* __restrict__ qg, const bf16* __restrict__ kg,
                           const bf16* __restrict__ vtg, bf16* __restrict__ og) {
    __shared__ alignas(16) bf16 Ks[64 * 72];
    __shared__ alignas(16) bf16 Vts[64 * 72];

    const int tid = threadIdx.x, lane = tid & 63, wave = tid >> 6;
    const int lo = lane & 15, hi = lane >> 4;

    const int bid = blockIdx.x;                 // 0..767
    const int xcd = bid & 7, idx = bid >> 3;
    const int head = xcd * 12 + (idx >> 3);     // 12 heads per XCD (K/V L2-sticky)
    const int q0 = (idx & 7) * 128;
    const int b = head / 12, h = head % 12;

    const size_t baseQK = (size_t)head * 1024 * 64;  // [B,H,N,D]
    const size_t baseVt = (size_t)head * 64 * 1024;  // [B,H,D,N]

    // Q frags (B-operand): col q = jq*16+lo, k = kk*32+hi*8+e. Pre-scale 1/8.
    bf16x8 qf[2][2];
#pragma unroll
    for (int jq = 0; jq < 2; ++jq)
#pragma unroll
        for (int kk = 0; kk < 2; ++kk) {
            bf16x8 v = *(const bf16x8*)&qg[baseQK +
                (size_t)(q0 + wave * 32 + jq * 16 + lo) * 64 + kk * 32 + hi * 8];
#pragma unroll
            for (int e = 0; e < 8; ++e) v[e] = (bf16)((float)v[e] * 0.125f);
            qf[jq][kk] = v;
        }

    f32x4 of[4][2] = {};          // O^T: d = jd*16+hi*4+r, q = jq*16+lo
    float lsum[2] = {0.f, 0.f};

    const int srow = tid >> 3;          // 0..31
    const int sc8  = (tid & 7) * 8;
    f32x4 kr[2], vr[2];

    // prologue: stage tile 0
#pragma unroll
    for (int s = 0; s < 2; ++s) {
        kr[s] = *(const f32x4*)&kg[baseQK + (size_t)(srow + 32 * s) * 64 + sc8];
        vr[s] = *(const f32x4*)&vtg[baseVt + (size_t)(srow + 32 * s) * 1024 + sc8];
    }
#pragma unroll
    for (int s = 0; s < 2; ++s) {
        *(f32x4*)&Ks[(srow + 32 * s) * 72 + sc8]  = kr[s];
        *(f32x4*)&Vts[(srow + 32 * s) * 72 + sc8] = vr[s];
    }

    for (int t = 0; t < 16; ++t) {
        __syncthreads();  // (a) tile t staged & visible

        if (t + 1 < 16) {  // T14: issue AFTER (a) -> drained at (b) post-compute
#pragma unroll
            for (int s = 0; s < 2; ++s) {
                kr[s] = *(const f32x4*)&kg[baseQK +
                    (size_t)((t + 1) * 64 + srow + 32 * s) * 64 + sc8];
                vr[s] = *(const f32x4*)&vtg[baseVt +
                    (size_t)(srow + 32 * s) * 1024 + (t + 1) * 64 + sc8];
            }
        }

        // K frags (A-operand): row kv = j*16+lo, k = kk*32+hi*8+e
        bf16x8 kf[4][2];
#pragma unroll
        for (int j = 0; j < 4; ++j)
#pragma unroll
            for (int kk = 0; kk < 2; ++kk)
                kf[j][kk] = *(const bf16x8*)&Ks[(j * 16 + lo) * 72 + kk * 32 + hi * 8];

        // S^T = K * Q^T (swapped): D[kv][q]
        __builtin_amdgcn_s_setprio(1);
        f32x4 st[4][2];
#pragma unroll
        for (int j = 0; j < 4; ++j)
#pragma unroll
            for (int jq = 0; jq < 2; ++jq) {
                f32x4 z = {0.f, 0.f, 0.f, 0.f};
                z = __builtin_amdgcn_mfma_f32_16x16x32_bf16(kf[j][0], qf[jq][0], z, 0, 0, 0);
                st[j][jq] = __builtin_amdgcn_mfma_f32_16x16x32_bf16(kf[j][1], qf[jq][1], z, 0, 0, 0);
            }
        __builtin_amdgcn_s_setprio(0);

        // static-max softmax: p = exp(S - 10); accumulate l; pack to bf16x4
        s16x4 pb[4][2];
#pragma unroll
        for (int j = 0; j < 4; ++j)
#pragma unroll
            for (int jq = 0; jq < 2; ++jq) {
                f32x4 p;
#pragma unroll
                for (int r = 0; r < 4; ++r) p[r] = __expf(st[j][jq][r] - 10.0f);
                lsum[jq] += (p[0] + p[1]) + (p[2] + p[3]);
                bf16x4 pk;
#pragma unroll
                for (int r = 0; r < 4; ++r) pk[r] = (bf16)p[r];
                pb[j][jq] = __builtin_bit_cast(s16x4, pk);
            }

        // PV (16x16x16, k = 16-kv slice j): of += Vt-frag * P^T-frag
        __builtin_amdgcn_s_setprio(1);
#pragma unroll
        for (int jd = 0; jd < 4; ++jd) {
#pragma unroll
            for (int j = 0; j < 4; ++j) {
                s16x4 va = *(const s16x4*)&Vts[(jd * 16 + lo) * 72 + j * 16 + hi * 4];
#pragma unroll
                for (int jq = 0; jq < 2; ++jq)
                    of[jd][jq] = mfma16x16x16bf16(va, pb[j][jq], of[jd][jq]);
            }
        }
        __builtin_amdgcn_s_setprio(0);

        __syncthreads();  // (b) all waves done reading t; drains t+1 loads (aged)
        if (t + 1 < 16) {
#pragma unroll
            for (int s = 0; s < 2; ++s) {
                *(f32x4*)&Ks[(srow + 32 * s) * 72 + sc8]  = kr[s];
                *(f32x4*)&Vts[(srow + 32 * s) * 72 + sc8] = vr[s];
            }
        }
    }

    // l: hi-groups hold disjoint kv partitions -> one butterfly at the end
#pragma unroll
    for (int jq = 0; jq < 2; ++jq) {
        lsum[jq] += __shfl_xor(lsum[jq], 16);
        lsum[jq] += __shfl_xor(lsum[jq], 32);
    }

    // O = O^T/l: lane q = jq*16+lo, d = jd*16+hi*4+r (8B stores)
#pragma unroll
    for (int jq = 0; jq < 2; ++jq) {
        float rl = 1.0f / lsum[jq];
        int n = q0 + wave * 32 + jq * 16 + lo;
#pragma unroll
        for (int jd = 0; jd < 4; ++jd) {
            bf16x4 o;
#pragma unroll
            for (int r = 0; r < 4; ++r) o[r] = (bf16)(of[jd][jq][r] * rl);
            *(bf16x4*)&og[((size_t)b * 1024 + n) * 768 + h * 64 + jd * 16 + hi * 4] = o;
        }
    }
}

// ---------------------------------------------------------------------------
extern "C" void kernel_launch(void* const* d_in, const int* in_sizes, int n_in,
                              void* d_out, int out_size, void* d_ws, size_t ws_size,
                              hipStream_t stream) {
    const float* x      = (const float*)d_in[0];
    const float* w_qkv  = (const float*)d_in[1];
    const float* w_proj = (const float*)d_in[2];
    const float* b_proj = (const float*)d_in[3];
    float* out = (float*)d_out;

    bf16* xb     = (bf16*)d_ws;
    bf16* wqkvb  = xb + (size_t)8192 * 768;
    bf16* wprojb = wqkvb + (size_t)2304 * 768;
    bf16* qb     = wprojb + (size_t)768 * 768;
    bf16* kb     = qb + (size_t)96 * 1024 * 64;
    bf16* vtb    = kb + (size_t)96 * 1024 * 64;
    bf16* aob    = vtb + (size_t)96 * 1024 * 64;

    cvt3_f32_bf16<<<1024, 256, 0, stream>>>(x, xb, 8192 * 768 / 8,
                                            w_qkv, wqkvb, 2304 * 768 / 8,
                                            w_proj, wprojb, 768 * 768 / 8);

    // QKV: [8192,2304] -> 32 m-tiles x 9 n-tiles = 288 blocks (8 XCD chunks of 36)
    gemm_bt<0, 9><<<288, 512, 0, stream>>>(xb, wqkvb, 768, qb, kb, vtb, nullptr, nullptr);
    flash_attn<<<768, 256, 0, stream>>>(qb, kb, vtb, aob);
    // proj: [8192,768] -> 32 x 3 = 96 blocks (8 XCD chunks of 12)
    gemm_bt<1, 3><<<96, 512, 0, stream>>>(aob, wprojb, 768, nullptr, nullptr, nullptr, out, b_proj);
}